// Round 3
// baseline (110.266 us; speedup 1.0000x reference)
//
#include <hip/hip_runtime.h>

// TriAffine: S[b,x,y,z] = sum_{i,k,j} xb[b,x,i] z[b,z,k] W[i,k,j] yb[b,y,j]
// B=2, L=256, N_IN=128. Output [2,256,256,256] f32 (134 MB).
//
// W[i][k][j] flattened over (k,j) is a contiguous N=16512 axis:
//  wtrans : Wt[n][i] bf16 (coalesced read of W, L2-merged 2B writes) + x,y,z->bf16
//  stage1 : A2[bx][n] = sum_{i<128} x[bx,i]*Wt[n][i] + Wt[n][128]   (flat GEMM, no LDS)
//  stage2 : per (b,x): stage A2 flat->LDS[k][152] (magic-div n->(k,j));
//           P'[k,y] = sum_j A2*y + A2[k,128]; S[y,z] = sum_k z*P'  (P' stays in regs)

typedef __bf16 bf16x8 __attribute__((ext_vector_type(8)));
typedef short short4_t __attribute__((ext_vector_type(4)));
typedef float f32x4 __attribute__((ext_vector_type(4)));
typedef unsigned short ushort4_t __attribute__((ext_vector_type(4)));

#define LL 256
#define NI 128
#define NFLAT 16512            // 128*129
#define WT_STRIDE 136          // Wt row stride (bf16): 272B, 16B-multiple
#define A2S_STRIDE 152         // stage2 LDS j-stride: 304B, 16B-multiple

__device__ __forceinline__ unsigned short f2bf(float f) {
    unsigned u = __builtin_bit_cast(unsigned, f);
    u += 0x7FFFu + ((u >> 16) & 1u);   // RNE
    return (unsigned short)(u >> 16);
}
__device__ __forceinline__ float bf2f(unsigned short h) {
    return __builtin_bit_cast(float, (unsigned)h << 16);
}

// ---------------- wtrans + prep ----------------
// blocks 0..128: Wt[n][i] = bf16(W[i][n]) for n-tile of 128, i in 0..128.
// blocks 129..320: x,y,z f32 -> bf16 (contiguous xyz buffer, 3*65536 elems).
__global__ __launch_bounds__(256) void wtrans_prep_kernel(const float* __restrict__ W,
                                                          const float* __restrict__ x,
                                                          const float* __restrict__ y,
                                                          const float* __restrict__ z,
                                                          unsigned short* __restrict__ Wt,
                                                          unsigned short* __restrict__ xyz) {
    const int blk = blockIdx.x, tid = threadIdx.x;
    if (blk < 129) {
        const int n0 = blk * 128 + ((tid & 31) << 2);
        const int isub = tid >> 5;
#pragma unroll 1
        for (int it = 0; it < 17; ++it) {
            int i = it * 8 + isub;
            if (i <= 128) {
                float4 v = *(const float4*)(W + (size_t)i * NFLAT + n0);
                Wt[(n0 + 0) * WT_STRIDE + i] = f2bf(v.x);
                Wt[(n0 + 1) * WT_STRIDE + i] = f2bf(v.y);
                Wt[(n0 + 2) * WT_STRIDE + i] = f2bf(v.z);
                Wt[(n0 + 3) * WT_STRIDE + i] = f2bf(v.w);
            }
        }
    } else {
        int t = (blk - 129) * 256 + tid;       // 0..49151 (192 blocks)
        int base = t * 4;                       // 0..196604
        int which = base >> 16;                 // 0,1,2
        int local = base & 65535;
        const float* s = (which == 0) ? x : (which == 1) ? y : z;
        float4 v = *(const float4*)(s + local);
        ushort4_t o;
        o[0] = f2bf(v.x); o[1] = f2bf(v.y); o[2] = f2bf(v.z); o[3] = f2bf(v.w);
        *(ushort4_t*)(xyz + base) = o;
    }
}

// ---------------- stage1: flat GEMM A2[bx][n] ----------------
// grid (4 bxg, 129 nb), 256 thr (4 waves). Wave: 32 n-rows x 128 bx-cols.
// D[n-row, bx-col]: A-op = Wt rows n (global, coalesced), B-op = x cols bx.
__global__ __launch_bounds__(256) void stage1_kernel(const unsigned short* __restrict__ Wt,
                                                     const unsigned short* __restrict__ xbf,
                                                     unsigned short* __restrict__ A2g) {
    const int bxg = blockIdx.x;            // 0..3
    const int nb  = blockIdx.y;            // 0..128
    const int tid = threadIdx.x;
    const int wv = tid >> 6, lane = tid & 63;
    const int l15 = lane & 15, h = lane >> 4;
    const int nbase = nb * 128 + wv * 32;

    bf16x8 af[2][4];
#pragma unroll
    for (int nt = 0; nt < 2; ++nt)
#pragma unroll
        for (int is = 0; is < 4; ++is)
            af[nt][is] = *(const bf16x8*)(Wt + (nbase + nt * 16 + l15) * WT_STRIDE + is * 32 + 8 * h);

    f32x4 acc[2][8];
#pragma unroll
    for (int nt = 0; nt < 2; ++nt) {
        f32x4 binit;
#pragma unroll
        for (int r = 0; r < 4; ++r)
            binit[r] = bf2f(Wt[(nbase + nt * 16 + 4 * h + r) * WT_STRIDE + 128]);  // bias W[128,n]
#pragma unroll
        for (int ct = 0; ct < 8; ++ct) acc[nt][ct] = binit;
    }

#pragma unroll
    for (int is = 0; is < 4; ++is)
#pragma unroll
        for (int ct = 0; ct < 8; ++ct) {
            bf16x8 xf = *(const bf16x8*)(xbf + (bxg * 128 + ct * 16 + l15) * NI + is * 32 + 8 * h);
            acc[0][ct] = __builtin_amdgcn_mfma_f32_16x16x32_bf16(af[0][is], xf, acc[0][ct], 0, 0, 0);
            acc[1][ct] = __builtin_amdgcn_mfma_f32_16x16x32_bf16(af[1][is], xf, acc[1][ct], 0, 0, 0);
        }

#pragma unroll
    for (int nt = 0; nt < 2; ++nt)
#pragma unroll
        for (int ct = 0; ct < 8; ++ct) {
            ushort4_t o;
#pragma unroll
            for (int r = 0; r < 4; ++r) o[r] = f2bf(acc[nt][ct][r]);
            *(ushort4_t*)(A2g + (size_t)(bxg * 128 + ct * 16 + l15) * NFLAT + nbase + nt * 16 + 4 * h) = o;
        }
}

// ---------------- stage2: per (b,x) block -> S[y,z] 256x256 ----------------
__global__ __launch_bounds__(512) void stage2_kernel(const unsigned short* __restrict__ ybf,
                                                     const unsigned short* __restrict__ zbf,
                                                     const unsigned short* __restrict__ A2g,
                                                     float* __restrict__ out) {
    const int bx  = blockIdx.x;            // b*256 + x
    const int b   = bx >> 8;
    const int tid = threadIdx.x;
    const int wv = tid >> 6, lane = tid & 63;
    const int l15 = lane & 15, h = lane >> 4;

    __shared__ unsigned short A2s[128 * A2S_STRIDE];   // 38912 B

    {   // stage flat A2[bx] -> padded LDS [k][152]; n = k*129 + j
        const unsigned short* src = A2g + (size_t)bx * NFLAT;
#pragma unroll 1
        for (int t = tid; t < NFLAT / 8; t += 512) {
            float4 raw = *(const float4*)(src + t * 8);
            const unsigned short* e = (const unsigned short*)&raw;
            int n0 = t * 8;
            int k = (int)(((unsigned)n0 * 65028u) >> 23);   // n/129, exact for n < 2^21
            int j = n0 - k * 129;
#pragma unroll
            for (int q = 0; q < 8; ++q) {
                A2s[k * A2S_STRIDE + j] = e[q];
                if (++j == 129) { j = 0; ++k; }
            }
        }
    }
    __syncthreads();

    const int y0 = wv * 32;
    const unsigned short* yb = ybf + b * LL * NI;
    const unsigned short* zb = zbf + b * LL * NI;

    // ---- Phase A: P'[k,y] = sum_j A2[k,j]*y[y,j] + A2[k,128] ----
    f32x4 accP[8][2];                      // [k-tile][y-tile]
#pragma unroll
    for (int kt = 0; kt < 8; ++kt)
#pragma unroll
        for (int r = 0; r < 4; ++r) {
            float bias = bf2f(A2s[(kt * 16 + 4 * h + r) * A2S_STRIDE + 128]);
            accP[kt][0][r] = bias; accP[kt][1][r] = bias;
        }
#pragma unroll
    for (int js = 0; js < 4; ++js) {
        bf16x8 yf[2];
#pragma unroll
        for (int yt = 0; yt < 2; ++yt)
            yf[yt] = *(const bf16x8*)(yb + (y0 + yt * 16 + l15) * NI + js * 32 + 8 * h);
#pragma unroll
        for (int kt = 0; kt < 8; ++kt) {
            bf16x8 af = *(const bf16x8*)&A2s[(kt * 16 + l15) * A2S_STRIDE + js * 32 + 8 * h];
            accP[kt][0] = __builtin_amdgcn_mfma_f32_16x16x32_bf16(af, yf[0], accP[kt][0], 0, 0, 0);
            accP[kt][1] = __builtin_amdgcn_mfma_f32_16x16x32_bf16(af, yf[1], accP[kt][1], 0, 0, 0);
        }
    }

    // ---- P' -> 16x16x16 B-operand frags (C-layout == B-layout) ----
    short4_t pf[8][2];
#pragma unroll
    for (int kt = 0; kt < 8; ++kt)
#pragma unroll
        for (int yt = 0; yt < 2; ++yt)
#pragma unroll
            for (int r = 0; r < 4; ++r)
                pf[kt][yt][r] = (short)f2bf(accP[kt][yt][r]);

    // ---- Phase B: S[y,z] = sum_k z[z,k]*P'[k,y] ----
    float* outb = out + (size_t)bx * (LL * LL);
#pragma unroll 1
    for (int zt = 0; zt < 16; ++zt) {
        f32x4 acc2[2];
#pragma unroll
        for (int yt = 0; yt < 2; ++yt) { acc2[yt][0] = 0.f; acc2[yt][1] = 0.f; acc2[yt][2] = 0.f; acc2[yt][3] = 0.f; }
#pragma unroll
        for (int kt = 0; kt < 8; ++kt) {
            short4_t zf = *(const short4_t*)(zb + (zt * 16 + l15) * NI + kt * 16 + 4 * h);
            acc2[0] = __builtin_amdgcn_mfma_f32_16x16x16bf16_1k(zf, pf[kt][0], acc2[0], 0, 0, 0);
            acc2[1] = __builtin_amdgcn_mfma_f32_16x16x16bf16_1k(zf, pf[kt][1], acc2[1], 0, 0, 0);
        }
#pragma unroll
        for (int yt = 0; yt < 2; ++yt) {
            int yy = y0 + yt * 16 + l15;
            *(f32x4*)(outb + yy * LL + zt * 16 + 4 * h) = acc2[yt];
        }
    }
}

extern "C" void kernel_launch(void* const* d_in, const int* in_sizes, int n_in,
                              void* d_out, int out_size, void* d_ws, size_t ws_size,
                              hipStream_t stream) {
    const float* x = (const float*)d_in[0];
    const float* y = (const float*)d_in[1];
    const float* z = (const float*)d_in[2];
    const float* W = (const float*)d_in[3];   // [129][128][129][1] = [129][16512]
    float* out = (float*)d_out;

    unsigned short* xbf = (unsigned short*)d_ws;             // 65536
    unsigned short* ybf = xbf + 65536;                       // 65536
    unsigned short* zbf = ybf + 65536;                       // 65536
    unsigned short* Wt  = zbf + 65536;                       // 16512*136 = 2245632 (~4.5 MB)
    unsigned short* A2g = Wt + (size_t)NFLAT * WT_STRIDE;    // 512*16512 (~16.9 MB)

    wtrans_prep_kernel<<<321, 256, 0, stream>>>(W, x, y, z, Wt, xbf);
    stage1_kernel<<<dim3(4, 129), 256, 0, stream>>>(Wt, xbf, A2g);
    stage2_kernel<<<512, 512, 0, stream>>>(ybf, zbf, A2g, out);
}

// Round 4
// 78.883 us; speedup vs baseline: 1.3978x; 1.3978x over previous
//
#include <hip/hip_runtime.h>

// TriAffine: S[b,x,y,z] = sum_{i,k,j} xb[b,x,i] z[b,z,k] W[i,k,j] yb[b,y,j]
// B=2, L=256, N_IN=128. Output [2,256,256,256] f32 (134 MB).
//
//  wtrans : Wt[n][i] bf16 (n=(k,j) flat axis) + x,y,z->bf16
//  stage1 : A2[bx][n] = sum_{i<128} x[bx,i]*Wt[n][i] + Wt[n][128]   (flat GEMM)
//  stage2 : per (b,x):  A2 flat->LDS[k][152];
//           phaseA: P'[k,y] = sum_j A2*y + A2[k,128]  (per-wave 32 y)
//           P' -> LDS [y][140] bf16 (reuses A2 region);
//           phaseB: wave owns 64 z x 128 y; z frags in regs (loaded once),
//                   P frags via ds_read_b64; S[y,z] = sum_k z*P'.

typedef __bf16 bf16x8 __attribute__((ext_vector_type(8)));
typedef short short4_t __attribute__((ext_vector_type(4)));
typedef float f32x4 __attribute__((ext_vector_type(4)));
typedef unsigned short ushort4_t __attribute__((ext_vector_type(4)));

#define LL 256
#define NI 128
#define NFLAT 16512            // 128*129
#define WT_STRIDE 136          // Wt row stride (bf16)
#define A2S_STRIDE 152         // stage2 LDS j-stride (A2 region)
#define P_STRIDE 140           // P' LDS k-stride: 280B rows, 8B-mult, b64 conflict-free

__device__ __forceinline__ unsigned short f2bf(float f) {
    unsigned u = __builtin_bit_cast(unsigned, f);
    u += 0x7FFFu + ((u >> 16) & 1u);   // RNE
    return (unsigned short)(u >> 16);
}
__device__ __forceinline__ float bf2f(unsigned short h) {
    return __builtin_bit_cast(float, (unsigned)h << 16);
}

// ---------------- wtrans + prep ----------------
__global__ __launch_bounds__(256) void wtrans_prep_kernel(const float* __restrict__ W,
                                                          const float* __restrict__ x,
                                                          const float* __restrict__ y,
                                                          const float* __restrict__ z,
                                                          unsigned short* __restrict__ Wt,
                                                          unsigned short* __restrict__ xyz) {
    const int blk = blockIdx.x, tid = threadIdx.x;
    if (blk < 129) {
        const int n0 = blk * 128 + ((tid & 31) << 2);
        const int isub = tid >> 5;
#pragma unroll    // full unroll: issue all 17 HBM loads up-front
        for (int it = 0; it < 17; ++it) {
            int i = it * 8 + isub;
            if (i <= 128) {
                float4 v = *(const float4*)(W + (size_t)i * NFLAT + n0);
                Wt[(n0 + 0) * WT_STRIDE + i] = f2bf(v.x);
                Wt[(n0 + 1) * WT_STRIDE + i] = f2bf(v.y);
                Wt[(n0 + 2) * WT_STRIDE + i] = f2bf(v.z);
                Wt[(n0 + 3) * WT_STRIDE + i] = f2bf(v.w);
            }
        }
    } else {
        int t = (blk - 129) * 256 + tid;       // 192 prep blocks
        int base = t * 4;
        int which = base >> 16;
        int local = base & 65535;
        const float* s = (which == 0) ? x : (which == 1) ? y : z;
        float4 v = *(const float4*)(s + local);
        ushort4_t o;
        o[0] = f2bf(v.x); o[1] = f2bf(v.y); o[2] = f2bf(v.z); o[3] = f2bf(v.w);
        *(ushort4_t*)(xyz + base) = o;
    }
}

// ---------------- stage1: flat GEMM A2[bx][n] ----------------
__global__ __launch_bounds__(256) void stage1_kernel(const unsigned short* __restrict__ Wt,
                                                     const unsigned short* __restrict__ xbf,
                                                     unsigned short* __restrict__ A2g) {
    const int bxg = blockIdx.x;            // 0..3
    const int nb  = blockIdx.y;            // 0..128
    const int tid = threadIdx.x;
    const int wv = tid >> 6, lane = tid & 63;
    const int l15 = lane & 15, h = lane >> 4;
    const int nbase = nb * 128 + wv * 32;

    bf16x8 af[2][4];
#pragma unroll
    for (int nt = 0; nt < 2; ++nt)
#pragma unroll
        for (int is = 0; is < 4; ++is)
            af[nt][is] = *(const bf16x8*)(Wt + (nbase + nt * 16 + l15) * WT_STRIDE + is * 32 + 8 * h);

    f32x4 acc[2][8];
#pragma unroll
    for (int nt = 0; nt < 2; ++nt) {
        f32x4 binit;
#pragma unroll
        for (int r = 0; r < 4; ++r)
            binit[r] = bf2f(Wt[(nbase + nt * 16 + 4 * h + r) * WT_STRIDE + 128]);
#pragma unroll
        for (int ct = 0; ct < 8; ++ct) acc[nt][ct] = binit;
    }

#pragma unroll
    for (int is = 0; is < 4; ++is)
#pragma unroll
        for (int ct = 0; ct < 8; ++ct) {
            bf16x8 xf = *(const bf16x8*)(xbf + (bxg * 128 + ct * 16 + l15) * NI + is * 32 + 8 * h);
            acc[0][ct] = __builtin_amdgcn_mfma_f32_16x16x32_bf16(af[0][is], xf, acc[0][ct], 0, 0, 0);
            acc[1][ct] = __builtin_amdgcn_mfma_f32_16x16x32_bf16(af[1][is], xf, acc[1][ct], 0, 0, 0);
        }

#pragma unroll
    for (int nt = 0; nt < 2; ++nt)
#pragma unroll
        for (int ct = 0; ct < 8; ++ct) {
            ushort4_t o;
#pragma unroll
            for (int r = 0; r < 4; ++r) o[r] = f2bf(acc[nt][ct][r]);
            *(ushort4_t*)(A2g + (size_t)(bxg * 128 + ct * 16 + l15) * NFLAT + nbase + nt * 16 + 4 * h) = o;
        }
}

// ---------------- stage2: per (b,x) block -> S[y,z] 256x256 ----------------
__global__ __launch_bounds__(512, 4) void stage2_kernel(const unsigned short* __restrict__ ybf,
                                                        const unsigned short* __restrict__ zbf,
                                                        const unsigned short* __restrict__ A2g,
                                                        float* __restrict__ out) {
    const int bx  = blockIdx.x;            // b*256 + x
    const int b   = bx >> 8;
    const int tid = threadIdx.x;
    const int wv = tid >> 6, lane = tid & 63;
    const int l15 = lane & 15, h = lane >> 4;

    __shared__ unsigned short SH[LL * P_STRIDE];   // 71680 B; A2 region aliased on top

    {   // stage flat A2[bx] -> padded LDS [k][152]; n = k*129 + j
        const unsigned short* src = A2g + (size_t)bx * NFLAT;
#pragma unroll 1
        for (int t = tid; t < NFLAT / 8; t += 512) {
            float4 raw = *(const float4*)(src + t * 8);
            const unsigned short* e = (const unsigned short*)&raw;
            int n0 = t * 8;
            int k = (int)(((unsigned)n0 * 65028u) >> 23);   // n/129
            int j = n0 - k * 129;
#pragma unroll
            for (int q = 0; q < 8; ++q) {
                SH[k * A2S_STRIDE + j] = e[q];
                if (++j == 129) { j = 0; ++k; }
            }
        }
    }
    __syncthreads();

    const int y0 = wv * 32;
    const unsigned short* yb = ybf + b * LL * NI;
    const unsigned short* zb = zbf + b * LL * NI;

    // ---- Phase A: P'[k,y] = sum_j A2[k,j]*y[y,j] + A2[k,128] ----
    f32x4 accP[8][2];                      // [k-tile][y-tile]; lane: y=l15(col), k=4h+r(row)
#pragma unroll
    for (int kt = 0; kt < 8; ++kt)
#pragma unroll
        for (int r = 0; r < 4; ++r) {
            float bias = bf2f(SH[(kt * 16 + 4 * h + r) * A2S_STRIDE + 128]);
            accP[kt][0][r] = bias; accP[kt][1][r] = bias;
        }
#pragma unroll
    for (int js = 0; js < 4; ++js) {
        bf16x8 yf[2];
#pragma unroll
        for (int yt = 0; yt < 2; ++yt)
            yf[yt] = *(const bf16x8*)(yb + (y0 + yt * 16 + l15) * NI + js * 32 + 8 * h);
#pragma unroll
        for (int kt = 0; kt < 8; ++kt) {
            bf16x8 af = *(const bf16x8*)&SH[(kt * 16 + l15) * A2S_STRIDE + js * 32 + 8 * h];
            accP[kt][0] = __builtin_amdgcn_mfma_f32_16x16x32_bf16(af, yf[0], accP[kt][0], 0, 0, 0);
            accP[kt][1] = __builtin_amdgcn_mfma_f32_16x16x32_bf16(af, yf[1], accP[kt][1], 0, 0, 0);
        }
    }
    __syncthreads();   // all waves done reading A2 region

    // ---- P' -> LDS [y][P_STRIDE] bf16 (k-major in row) ----
#pragma unroll
    for (int kt = 0; kt < 8; ++kt)
#pragma unroll
        for (int yt = 0; yt < 2; ++yt) {
            unsigned lo = (unsigned)f2bf(accP[kt][yt][0]) | ((unsigned)f2bf(accP[kt][yt][1]) << 16);
            unsigned hi = (unsigned)f2bf(accP[kt][yt][2]) | ((unsigned)f2bf(accP[kt][yt][3]) << 16);
            uint2 v; v.x = lo; v.y = hi;
            *(uint2*)&SH[(y0 + yt * 16 + l15) * P_STRIDE + kt * 16 + 4 * h] = v;
        }

    // z fragments: wave owns 64 z-rows, loaded ONCE (overlaps ds_writes above)
    const int zg = wv & 3, yh = wv >> 2;
    const int z0 = zg * 64;
    short4_t zf[4][8];
#pragma unroll
    for (int zt = 0; zt < 4; ++zt)
#pragma unroll
        for (int kt = 0; kt < 8; ++kt)
            zf[zt][kt] = *(const short4_t*)(zb + (z0 + zt * 16 + l15) * NI + kt * 16 + 4 * h);

    __syncthreads();   // P' visible

    // ---- Phase B: S[y,z] = sum_k z[z,k]*P'[k,y]; wave: 64 z x 128 y ----
    float* outb = out + (size_t)bx * (LL * LL);
#pragma unroll 1
    for (int yti = 0; yti < 8; ++yti) {
        const int yy = yh * 128 + yti * 16 + l15;    // this lane's y (col)
        f32x4 acc2[4];
#pragma unroll
        for (int zt = 0; zt < 4; ++zt) { acc2[zt][0] = 0.f; acc2[zt][1] = 0.f; acc2[zt][2] = 0.f; acc2[zt][3] = 0.f; }
#pragma unroll
        for (int kt = 0; kt < 8; ++kt) {
            short4_t pB = *(const short4_t*)&SH[yy * P_STRIDE + kt * 16 + 4 * h];
#pragma unroll
            for (int zt = 0; zt < 4; ++zt)
                acc2[zt] = __builtin_amdgcn_mfma_f32_16x16x16bf16_1k(zf[zt][kt], pB, acc2[zt], 0, 0, 0);
        }
#pragma unroll
        for (int zt = 0; zt < 4; ++zt)
            *(f32x4*)(outb + (size_t)yy * LL + z0 + zt * 16 + 4 * h) = acc2[zt];
    }
}

extern "C" void kernel_launch(void* const* d_in, const int* in_sizes, int n_in,
                              void* d_out, int out_size, void* d_ws, size_t ws_size,
                              hipStream_t stream) {
    const float* x = (const float*)d_in[0];
    const float* y = (const float*)d_in[1];
    const float* z = (const float*)d_in[2];
    const float* W = (const float*)d_in[3];   // [129][128][129][1] = [129][16512]
    float* out = (float*)d_out;

    unsigned short* xbf = (unsigned short*)d_ws;             // 65536
    unsigned short* ybf = xbf + 65536;                       // 65536
    unsigned short* zbf = ybf + 65536;                       // 65536
    unsigned short* Wt  = zbf + 65536;                       // ~4.5 MB
    unsigned short* A2g = Wt + (size_t)NFLAT * WT_STRIDE;    // ~16.9 MB

    wtrans_prep_kernel<<<321, 256, 0, stream>>>(W, x, y, z, Wt, xbf);
    stage1_kernel<<<dim3(4, 129), 256, 0, stream>>>(Wt, xbf, A2g);
    stage2_kernel<<<512, 512, 0, stream>>>(ybf, zbf, A2g, out);
}